// Round 1
// baseline (107.099 us; speedup 1.0000x reference)
//
#include <hip/hip_runtime.h>
#include <hip/hip_bf16.h>

// Elementwise: out = relu((x + 2) * 3 - 4), fp32 in / fp32 out.
// N = 32*2048*1024 = 67,108,864 (divisible by 4) -> float4 path, no tail.

__global__ void __launch_bounds__(256) fused_affine_relu_kernel(
    const float4* __restrict__ in, float4* __restrict__ out, int n4) {
    int idx = blockIdx.x * blockDim.x + threadIdx.x;
    int stride = gridDim.x * blockDim.x;
    for (int i = idx; i < n4; i += stride) {
        float4 v = in[i];
        float4 r;
        r.x = fmaxf((v.x + 2.0f) * 3.0f - 4.0f, 0.0f);
        r.y = fmaxf((v.y + 2.0f) * 3.0f - 4.0f, 0.0f);
        r.z = fmaxf((v.z + 2.0f) * 3.0f - 4.0f, 0.0f);
        r.w = fmaxf((v.w + 2.0f) * 3.0f - 4.0f, 0.0f);
        out[i] = r;
    }
}

extern "C" void kernel_launch(void* const* d_in, const int* in_sizes, int n_in,
                              void* d_out, int out_size, void* d_ws, size_t ws_size,
                              hipStream_t stream) {
    const float* in = (const float*)d_in[0];
    float* out = (float*)d_out;
    int n = in_sizes[0];
    int n4 = n / 4;  // 16,777,216 — exact, no remainder

    const int block = 256;
    int blocks = (n4 + block - 1) / block;
    if (blocks > 2048) blocks = 2048;  // grid-stride the rest (256 CU * 8 blocks)

    fused_affine_relu_kernel<<<blocks, block, 0, stream>>>(
        (const float4*)in, (float4*)out, n4);
}

// Round 2
// 87.605 us; speedup vs baseline: 1.2225x; 1.2225x over previous
//
#include <hip/hip_runtime.h>
#include <hip/hip_bf16.h>

// Elementwise: out = relu((x + 2) * 3 - 4) = relu(3x + 2), fp32 -> fp32.
// N = 32*2048*1024 = 67,108,864 = 16384 blocks * 256 threads * 4 float4.

typedef float f32x4 __attribute__((ext_vector_type(4)));

__device__ __forceinline__ f32x4 affine_relu(f32x4 v) {
    f32x4 r;
    r.x = fmaxf(fmaf(v.x, 3.0f, 2.0f), 0.0f);
    r.y = fmaxf(fmaf(v.y, 3.0f, 2.0f), 0.0f);
    r.z = fmaxf(fmaf(v.z, 3.0f, 2.0f), 0.0f);
    r.w = fmaxf(fmaf(v.w, 3.0f, 2.0f), 0.0f);
    return r;
}

// Exact-fit path: each thread handles 4 float4 (64 B), 4 independent loads
// in flight (MLP), non-temporal to bypass cache pollution (no reuse).
__global__ void __launch_bounds__(256) fused_affine_relu_x4(
    const f32x4* __restrict__ in, f32x4* __restrict__ out) {
    int i = blockIdx.x * 1024 + threadIdx.x;  // 1024 = 256 threads * 4
    f32x4 v0 = __builtin_nontemporal_load(in + i);
    f32x4 v1 = __builtin_nontemporal_load(in + i + 256);
    f32x4 v2 = __builtin_nontemporal_load(in + i + 512);
    f32x4 v3 = __builtin_nontemporal_load(in + i + 768);
    __builtin_nontemporal_store(affine_relu(v0), out + i);
    __builtin_nontemporal_store(affine_relu(v1), out + i + 256);
    __builtin_nontemporal_store(affine_relu(v2), out + i + 512);
    __builtin_nontemporal_store(affine_relu(v3), out + i + 768);
}

// Fallback for any shape not divisible by 4096 floats (not hit for this problem).
__global__ void __launch_bounds__(256) fused_affine_relu_tail(
    const float* __restrict__ in, float* __restrict__ out, int start, int n) {
    int i = start + blockIdx.x * blockDim.x + threadIdx.x;
    if (i < n) out[i] = fmaxf(fmaf(in[i], 3.0f, 2.0f), 0.0f);
}

extern "C" void kernel_launch(void* const* d_in, const int* in_sizes, int n_in,
                              void* d_out, int out_size, void* d_ws, size_t ws_size,
                              hipStream_t stream) {
    const float* in = (const float*)d_in[0];
    float* out = (float*)d_out;
    int n = in_sizes[0];

    const int elems_per_block = 256 * 16;  // 4096 floats per block
    int main_blocks = n / elems_per_block; // 16384 for this problem
    if (main_blocks > 0) {
        fused_affine_relu_x4<<<main_blocks, 256, 0, stream>>>(
            (const f32x4*)in, (f32x4*)out);
    }
    int done = main_blocks * elems_per_block;
    int rem = n - done;
    if (rem > 0) {
        int tb = (rem + 255) / 256;
        fused_affine_relu_tail<<<tb, 256, 0, stream>>>(in, out, done, n);
    }
}